// Round 25
// baseline (898.395 us; speedup 1.0000x reference)
//
#include <hip/hip_runtime.h>

// B=16384, FEAT=1024, FD=256, M=4 nodes, H1=4x128 (concat->512), H2=1x256, OUT=8.
// Round 25: r24 base (best, 323.7us) + ONE change: 3-ahead register prefetch
// in gemm_h8 (issue tile k+3 in iter k; ds_write tile k+1 from regs loaded
// TWO iterations ago -> issue-to-use ~600-800cy, covering HBM latency).
// Invariant: tile t -> register set t&1 -> LDS buffer t&1. Bit-identical math.

typedef __attribute__((ext_vector_type(8))) _Float16 f16x8;
typedef __attribute__((ext_vector_type(4))) float f32x4;

struct P4 { const void* p[4]; };

#define SYM(i,j) ((i)*(7-(i))/2 + (j))

__device__ __forceinline__ float sigmoidf_(float x) { return 1.0f / (1.0f + __expf(-x)); }
__device__ __forceinline__ float gelu_(float x) {
    return 0.5f * x * (1.0f + erff(x * 0.70710678118654752440f));
}

// ---- MFMA NT GEMM, 512 threads = 8 waves (2 row x 4 col), BM=BN=128, BK=32 --
// A fp32 (cvt at ds_write) or fp16 (direct); W fp32 (cvt at ds_write);
// C fp32 (scattered) or fp16 (LDS-transpose epilogue). SWZ: XCD chunked remap.
// 3-ahead pipeline: per iter k: [ds_write t=k+1 from set (k+1)&1] ->
// [issue loads t=k+3 into set (k+3)&1 == (k+1)&1] -> [MFMA buf k&1] -> barrier.
template<int ACT, bool A_F32, bool OUT_F16, bool HAS_BIAS, bool SWZ>
__global__ __launch_bounds__(512)
void gemm_h8(P4 A4, P4 W4, P4 b4, void* __restrict__ Cv,
             int K, int lda, int ldc, int zofs)
{
    __shared__ __align__(16) unsigned char smem[32768];
    _Float16 (*As)[128][32] = (_Float16(*)[128][32])smem;            // [2][128][32]
    _Float16 (*Bs)[128][32] = (_Float16(*)[128][32])(smem + 16384);  // [2][128][32]
    _Float16 (*outT)[128]   = (_Float16(*)[128])smem;                // [128][128] alias

    const int z = blockIdx.z;
    const float* __restrict__ bias = (const float*)b4.p[z];
    const float* __restrict__ Bw   = (const float*)W4.p[z];

    int bx = blockIdx.x, by = blockIdx.y;
    if constexpr (SWZ) {
        const int nxy  = gridDim.x * gridDim.y;
        const int flat = by * gridDim.x + bx;
        const int chunk = nxy >> 3;
        const int swz = (flat & 7) * chunk + (flat >> 3);
        bx = swz % gridDim.x;
        by = swz / gridDim.x;
    }

    const int t    = threadIdx.x;
    const int lane = t & 63;
    const int w    = t >> 6;
    const int wr   = (w >> 2) << 6;
    const int wc   = (w & 3) << 5;
    const long rowA = (long)by * 128;
    const long colB = (long)bx * 128;

    const float* Bpt[2];
    int brr[2], bcc[2];
    #pragma unroll
    for (int i = 0; i < 2; ++i) {
        const int f = t + i * 512;
        brr[i] = f >> 3;
        bcc[i] = (f & 7) << 2;
        Bpt[i] = Bw + (colB + brr[i]) * (long)K + bcc[i];
    }
    const float* Apt32[2]; int arr[2], acc_[2];
    const _Float16* Apt16 = nullptr; int a16r = 0, a16c = 0;
    if constexpr (A_F32) {
        const float* A = (const float*)A4.p[z];
        #pragma unroll
        for (int i = 0; i < 2; ++i) {
            const int f = t + i * 512;
            arr[i] = f >> 3;
            acc_[i] = (f & 7) << 2;
            Apt32[i] = A + (rowA + arr[i]) * (long)lda + acc_[i];
        }
    } else {
        const _Float16* A = (const _Float16*)A4.p[z];
        a16r = t >> 2;
        a16c = (t & 3) << 3;
        Apt16 = A + (rowA + a16r) * (long)lda + a16c;
    }

    f32x4 acc[4][2] = {};
    const int NK = K >> 5;

    // two register sets; tile t lives in set t&1
    float4 aS32[2][2], bS[2][2];
    uint4  aS16[2] = {};

    // ---- prologue: tile 0 -> set0 -> LDS buf0; tile 1 -> set1; tile 2 -> set0
    if constexpr (A_F32) {
        #pragma unroll
        for (int i = 0; i < 2; ++i) aS32[0][i] = *(const float4*)(Apt32[i]);
    } else {
        aS16[0] = *(const uint4*)(Apt16);
    }
    #pragma unroll
    for (int i = 0; i < 2; ++i) bS[0][i] = *(const float4*)(Bpt[i]);

    if constexpr (A_F32) {
        #pragma unroll
        for (int i = 0; i < 2; ++i) {
            union { _Float16 h[4]; uint2 u; } pa;
            pa.h[0] = (_Float16)aS32[0][i].x; pa.h[1] = (_Float16)aS32[0][i].y;
            pa.h[2] = (_Float16)aS32[0][i].z; pa.h[3] = (_Float16)aS32[0][i].w;
            *(uint2*)&As[0][arr[i]][acc_[i]] = pa.u;
        }
    } else {
        *(uint4*)&As[0][a16r][a16c] = aS16[0];
    }
    #pragma unroll
    for (int i = 0; i < 2; ++i) {
        union { _Float16 h[4]; uint2 u; } pb;
        pb.h[0] = (_Float16)bS[0][i].x; pb.h[1] = (_Float16)bS[0][i].y;
        pb.h[2] = (_Float16)bS[0][i].z; pb.h[3] = (_Float16)bS[0][i].w;
        *(uint2*)&Bs[0][brr[i]][bcc[i]] = pb.u;
    }
    if (NK > 1) {       // tile 1 -> set 1
        if constexpr (A_F32) {
            #pragma unroll
            for (int i = 0; i < 2; ++i) aS32[1][i] = *(const float4*)(Apt32[i] + 32);
        } else {
            aS16[1] = *(const uint4*)(Apt16 + 32);
        }
        #pragma unroll
        for (int i = 0; i < 2; ++i) bS[1][i] = *(const float4*)(Bpt[i] + 32);
    }
    if (NK > 2) {       // tile 2 -> set 0 (buf0 already written)
        if constexpr (A_F32) {
            #pragma unroll
            for (int i = 0; i < 2; ++i) aS32[0][i] = *(const float4*)(Apt32[i] + 64);
        } else {
            aS16[0] = *(const uint4*)(Apt16 + 64);
        }
        #pragma unroll
        for (int i = 0; i < 2; ++i) bS[0][i] = *(const float4*)(Bpt[i] + 64);
    }
    __syncthreads();

    const int fr = lane & 15;
    const int fq = lane >> 4;
    const int fg = fq << 3;

    for (int kk = 0; kk < NK; ++kk) {
        const int cur = kk & 1, nxt = cur ^ 1;   // nxt == (kk+1)&1 == its set

        // 1) ds_write tile kk+1 (regs issued two iterations ago) -> buf[nxt]
        if (kk + 1 < NK) {
            if constexpr (A_F32) {
                #pragma unroll
                for (int i = 0; i < 2; ++i) {
                    union { _Float16 h[4]; uint2 u; } pa;
                    pa.h[0] = (_Float16)aS32[nxt][i].x; pa.h[1] = (_Float16)aS32[nxt][i].y;
                    pa.h[2] = (_Float16)aS32[nxt][i].z; pa.h[3] = (_Float16)aS32[nxt][i].w;
                    *(uint2*)&As[nxt][arr[i]][acc_[i]] = pa.u;
                }
            } else {
                *(uint4*)&As[nxt][a16r][a16c] = aS16[nxt];
            }
            #pragma unroll
            for (int i = 0; i < 2; ++i) {
                union { _Float16 h[4]; uint2 u; } pb;
                pb.h[0] = (_Float16)bS[nxt][i].x; pb.h[1] = (_Float16)bS[nxt][i].y;
                pb.h[2] = (_Float16)bS[nxt][i].z; pb.h[3] = (_Float16)bS[nxt][i].w;
                *(uint2*)&Bs[nxt][brr[i]][bcc[i]] = pb.u;
            }
        }

        // 2) issue loads for tile kk+3 into the set just consumed (== nxt)
        if (kk + 3 < NK) {
            const int ko = (kk + 3) << 5;
            if constexpr (A_F32) {
                #pragma unroll
                for (int i = 0; i < 2; ++i) aS32[nxt][i] = *(const float4*)(Apt32[i] + ko);
            } else {
                aS16[nxt] = *(const uint4*)(Apt16 + ko);
            }
            #pragma unroll
            for (int i = 0; i < 2; ++i) bS[nxt][i] = *(const float4*)(Bpt[i] + ko);
        }

        // 3) fragments + MFMA on buf[cur]
        f16x8 af[4], bf[2];
        #pragma unroll
        for (int m = 0; m < 4; ++m) af[m] = *(const f16x8*)&As[cur][wr + m*16 + fr][fg];
        #pragma unroll
        for (int n = 0; n < 2; ++n) bf[n] = *(const f16x8*)&Bs[cur][wc + n*16 + fr][fg];
        #pragma unroll
        for (int m = 0; m < 4; ++m)
            #pragma unroll
            for (int n = 0; n < 2; ++n)
                acc[m][n] = __builtin_amdgcn_mfma_f32_16x16x32_f16(af[m], bf[n], acc[m][n], 0, 0, 0);

        // 4) barrier
        __syncthreads();
    }

    if constexpr (OUT_F16) {
        _Float16* Cz = (_Float16*)Cv + (long)z * zofs;
        __syncthreads();
        float bn[2];
        #pragma unroll
        for (int n = 0; n < 2; ++n)
            bn[n] = HAS_BIAS ? bias[colB + wc + n*16 + fr] : 0.0f;
        #pragma unroll
        for (int m = 0; m < 4; ++m)
            #pragma unroll
            for (int n = 0; n < 2; ++n)
                #pragma unroll
                for (int j = 0; j < 4; ++j) {
                    float x = acc[m][n][j] + bn[n];
                    if (ACT == 1) x = fmaxf(x, 0.0f);
                    outT[wr + m*16 + fq*4 + j][wc + n*16 + fr] = (_Float16)x;
                }
        __syncthreads();
        #pragma unroll
        for (int i = 0; i < 4; ++i) {
            const int s = t + i * 512;
            const int r = s >> 4, c = (s & 15) << 3;
            *(uint4*)(Cz + (rowA + r) * (long)ldc + colB + c) = *(const uint4*)&outT[r][c];
        }
    } else {
        float* Cz = (float*)Cv + (long)z * zofs;
        #pragma unroll
        for (int n = 0; n < 2; ++n) {
            const long col = colB + wc + n*16 + fr;
            const float bn = HAS_BIAS ? bias[col] : 0.0f;
            #pragma unroll
            for (int m = 0; m < 4; ++m) {
                const long row0 = rowA + wr + m*16 + fq*4;
                #pragma unroll
                for (int j = 0; j < 4; ++j) {
                    float x = acc[m][n][j] + bn;
                    if (ACT == 1) x = fmaxf(x, 0.0f);
                    Cz[(row0 + j) * (long)ldc + col] = x;
                }
            }
        }
    }
}

// -- GAT1 attention (r24 verbatim): fp16 in, fp32 compute, fp16 out ----------
__global__ __launch_bounds__(256)
void gat1_attn_kernel(const _Float16* __restrict__ h1f,
                      _Float16* __restrict__ h1x,
                      const int* __restrict__ missing,
                      const float* __restrict__ attl, const float* __restrict__ attr,
                      const float* __restrict__ bias)
{
    const int gtid = blockIdx.x * 256 + threadIdx.x;
    const int wid  = gtid >> 6;
    const int lane = threadIdx.x & 63;
    const int b = wid >> 2;
    const int h = wid & 3;
    const int cb = h * 128 + lane;
    const _Float16* bi = h1f + (size_t)b * 2048 + cb;
    _Float16*       bo = h1x + (size_t)b * 2048 + cb;

    float hr[4][2];
    #pragma unroll
    for (int j = 0; j < 4; ++j) {
        hr[j][0] = (float)bi[j*512];
        hr[j][1] = (float)bi[j*512 + 64];
    }
    const float al0 = attl[cb], al1 = attl[cb+64];
    const float ar0 = attr[cb], ar1 = attr[cb+64];

    float red[18];
    #pragma unroll
    for (int i = 0; i < 4; ++i)
        #pragma unroll
        for (int j = i; j < 4; ++j)
            red[SYM(i,j)] = hr[i][0]*hr[j][0] + hr[i][1]*hr[j][1];
    #pragma unroll
    for (int j = 0; j < 4; ++j) {
        red[10+j] = hr[j][0]*al0 + hr[j][1]*al1;
        red[14+j] = hr[j][0]*ar0 + hr[j][1]*ar1;
    }
    #pragma unroll
    for (int m = 1; m < 64; m <<= 1)
        #pragma unroll
        for (int r = 0; r < 18; ++r)
            red[r] += __shfl_xor(red[r], m, 64);

    const int miss = missing[b];
    bool pres[4];
    #pragma unroll
    for (int mm = 0; mm < 4; ++mm) pres[mm] = (miss != mm + 1);

    float attn[4][4];
    #pragma unroll
    for (int i = 0; i < 4; ++i) {
        float av[4]; float mx = -3.4e38f;
        #pragma unroll
        for (int j = 0; j < 4; ++j) {
            const bool mk = (i == j) || (pres[i] && pres[j]);
            const float l = (i <= j) ? red[SYM(i,j)] : red[SYM(j,i)];
            float v = (red[14+i] + red[10+j]) * sigmoidf_(l);
            v = (v >= 0.0f) ? v : 0.2f * v;
            av[j] = mk ? v : -1e30f;
            mx = fmaxf(mx, av[j]);
        }
        float den = 0.0f;
        #pragma unroll
        for (int j = 0; j < 4; ++j) { av[j] = __expf(av[j] - mx); den += av[j]; }
        const float inv = 1.0f / den;
        #pragma unroll
        for (int j = 0; j < 4; ++j) attn[i][j] = av[j] * inv;
    }

    const float b0 = bias[cb], b1 = bias[cb+64];
    #pragma unroll
    for (int i = 0; i < 4; ++i) {
        float o0 = b0, o1 = b1;
        #pragma unroll
        for (int j = 0; j < 4; ++j) { o0 += attn[i][j]*hr[j][0]; o1 += attn[i][j]*hr[j][1]; }
        bo[i*512]      = (_Float16)gelu_(o0);
        bo[i*512 + 64] = (_Float16)gelu_(o1);
    }
}

// ------- GAT2 attention + pool + LayerNorm (r24 verbatim): fp16 in/out -------
__global__ __launch_bounds__(256)
void gat2_attn_kernel(const _Float16* __restrict__ h2h,
                      const int* __restrict__ missing,
                      const float* __restrict__ attl, const float* __restrict__ attr,
                      const float* __restrict__ bias,
                      const float* __restrict__ lng, const float* __restrict__ lnb,
                      _Float16* __restrict__ normed)
{
    const int gtid = blockIdx.x * 256 + threadIdx.x;
    const int b = gtid >> 6;
    const int lane = threadIdx.x & 63;
    const _Float16* hp = h2h + (size_t)b * 1024;

    float4 hr[4];
    #pragma unroll
    for (int j = 0; j < 4; ++j) {
        union { uint2 u; _Float16 h[4]; } v;
        v.u = *(const uint2*)(hp + j * 256 + lane * 4);
        hr[j].x = (float)v.h[0]; hr[j].y = (float)v.h[1];
        hr[j].z = (float)v.h[2]; hr[j].w = (float)v.h[3];
    }
    const float4 al = ((const float4*)attl)[lane];
    const float4 ar = ((const float4*)attr)[lane];

    float red[18];
    #pragma unroll
    for (int i = 0; i < 4; ++i)
        #pragma unroll
        for (int j = i; j < 4; ++j)
            red[SYM(i,j)] = hr[i].x*hr[j].x + hr[i].y*hr[j].y + hr[i].z*hr[j].z + hr[i].w*hr[j].w;
    #pragma unroll
    for (int j = 0; j < 4; ++j) {
        red[10+j] = hr[j].x*al.x + hr[j].y*al.y + hr[j].z*al.z + hr[j].w*al.w;
        red[14+j] = hr[j].x*ar.x + hr[j].y*ar.y + hr[j].z*ar.z + hr[j].w*ar.w;
    }
    #pragma unroll
    for (int m = 1; m < 64; m <<= 1)
        #pragma unroll
        for (int r = 0; r < 18; ++r)
            red[r] += __shfl_xor(red[r], m, 64);

    const int miss = missing[b];
    bool pres[4];
    #pragma unroll
    for (int mm = 0; mm < 4; ++mm) pres[mm] = (miss != mm + 1);

    float wsum[4] = {0.f, 0.f, 0.f, 0.f};
    #pragma unroll
    for (int i = 0; i < 4; ++i) {
        float av[4]; float mx = -3.4e38f;
        #pragma unroll
        for (int j = 0; j < 4; ++j) {
            const bool mk = (i == j) || (pres[i] && pres[j]);
            const float l = (i <= j) ? red[SYM(i,j)] : red[SYM(j,i)];
            float v = (red[14+i] + red[10+j]) * sigmoidf_(l);
            v = (v >= 0.0f) ? v : 0.2f * v;
            av[j] = mk ? v : -1e30f;
            mx = fmaxf(mx, av[j]);
        }
        float den = 0.0f;
        #pragma unroll
        for (int j = 0; j < 4; ++j) { av[j] = __expf(av[j] - mx); den += av[j]; }
        const float inv = 0.25f / den;
        #pragma unroll
        for (int j = 0; j < 4; ++j) wsum[j] += av[j] * inv;
    }

    const float4 bv = ((const float4*)bias)[lane];
    float pooled[4] = {bv.x, bv.y, bv.z, bv.w};
    #pragma unroll
    for (int j = 0; j < 4; ++j) {
        pooled[0] += wsum[j] * hr[j].x;
        pooled[1] += wsum[j] * hr[j].y;
        pooled[2] += wsum[j] * hr[j].z;
        pooled[3] += wsum[j] * hr[j].w;
    }

    float s1 = pooled[0] + pooled[1] + pooled[2] + pooled[3];
    float s2 = pooled[0]*pooled[0] + pooled[1]*pooled[1] + pooled[2]*pooled[2] + pooled[3]*pooled[3];
    #pragma unroll
    for (int m = 1; m < 64; m <<= 1) {
        s1 += __shfl_xor(s1, m, 64);
        s2 += __shfl_xor(s2, m, 64);
    }
    const float mu   = s1 * (1.0f / 256.0f);
    const float var  = s2 * (1.0f / 256.0f) - mu * mu;
    const float rstd = rsqrtf(var + 1e-5f);
    const float4 g  = ((const float4*)lng)[lane];
    const float4 bb = ((const float4*)lnb)[lane];
    union { _Float16 h[4]; uint2 u; } o;
    o.h[0] = (_Float16)((pooled[0] - mu) * rstd * g.x + bb.x);
    o.h[1] = (_Float16)((pooled[1] - mu) * rstd * g.y + bb.y);
    o.h[2] = (_Float16)((pooled[2] - mu) * rstd * g.z + bb.z);
    o.h[3] = (_Float16)((pooled[3] - mu) * rstd * g.w + bb.w);
    *(uint2*)(normed + (size_t)b * 256 + lane * 4) = o.u;
}

// ---------------- head2 (round-4 verbatim): fp32 hid ------------------------
__global__ __launch_bounds__(256)
void head2_kernel(const float* __restrict__ hid, const float* __restrict__ W2,
                  const float* __restrict__ b2, float* __restrict__ out)
{
    const int t = blockIdx.x * 256 + threadIdx.x;
    const int b = t >> 3, o = t & 7;
    const float4* hp = (const float4*)(hid + (size_t)b * 256);
    const float4* wp = (const float4*)(W2 + o * 256);
    float acc = b2[o];
    #pragma unroll 8
    for (int c = 0; c < 64; ++c) {
        const float4 hv = hp[c], wv = wp[c];
        acc += hv.x*wv.x + hv.y*wv.y + hv.z*wv.z + hv.w*wv.w;
    }
    out[t] = acc;
}

// ---------------- launch ----------------------------------------------------
extern "C" void kernel_launch(void* const* d_in, const int* in_sizes, int n_in,
                              void* d_out, int out_size, void* d_ws, size_t ws_size,
                              hipStream_t stream)
{
    (void)in_sizes; (void)n_in; (void)out_size; (void)ws_size;
    const int*   miss  = (const int*)d_in[4];
    const float* g1_al = (const float*)d_in[14];
    const float* g1_ar = (const float*)d_in[15];
    const float* g1_b  = (const float*)d_in[16];
    const float* g2_al = (const float*)d_in[18];
    const float* g2_ar = (const float*)d_in[19];
    const float* g2_b  = (const float*)d_in[20];
    const float* ln_g  = (const float*)d_in[21];
    const float* ln_b  = (const float*)d_in[22];
    const float* h_W2  = (const float*)d_in[25];
    const float* h_b2  = (const float*)d_in[26];
    float* out = (float*)d_out;

    // workspace (MiB offsets; peak 160 MiB, r24 layout):
    char* base = (char*)d_ws;
    _Float16* feats  = (_Float16*)base;
    _Float16* h1f    = (_Float16*)(base + (64ll  << 20));
    _Float16* h1x    = (_Float16*)base;
    _Float16* h2h    = (_Float16*)(base + (128ll << 20));
    _Float16* normed = (_Float16*)(base + (64ll  << 20));
    float*    hid    = (float*)   (base + (80ll  << 20));

    const dim3 blkG(512);
    const dim3 blk(256);

    P4 Xs  = {{d_in[0], d_in[1], d_in[2], d_in[3]}};
    P4 Wms = {{d_in[5], d_in[7], d_in[9], d_in[11]}};
    P4 bms = {{d_in[6], d_in[8], d_in[10], d_in[12]}};
    P4 F4  = {{feats, feats, feats, feats}};
    P4 G1W = {{d_in[13], d_in[13], d_in[13], d_in[13]}};
    P4 H1X = {{h1x, h1x, h1x, h1x}};
    P4 G2W = {{d_in[17], d_in[17], d_in[17], d_in[17]}};
    P4 N4  = {{normed, normed, normed, normed}};
    P4 HW1 = {{d_in[23], d_in[23], d_in[23], d_in[23]}};
    P4 HB1 = {{d_in[24], d_in[24], d_in[24], d_in[24]}};
    P4 NUL = {{nullptr, nullptr, nullptr, nullptr}};

    // 1) projections (z-batched, XCD-swizzled): feats fp16
    gemm_h8<0, true, true, true, true><<<dim3(2, 128, 4), blkG, 0, stream>>>(
        Xs, Wms, bms, feats, /*K=*/1024, /*lda=*/1024, /*ldc=*/1024, /*zofs=*/256);

    // 2) gat1 linear (XCD-swizzled): h1f fp16 = feats(fp16) @ g1_W^T
    gemm_h8<0, false, true, false, true><<<dim3(4, 512, 1), blkG, 0, stream>>>(
        F4, G1W, NUL, h1f, 256, 256, 512, 0);

    // 3) gat1 attention + bias + gelu: h1f fp16 -> h1x fp16
    gat1_attn_kernel<<<dim3(16384), blk, 0, stream>>>(
        h1f, h1x, miss, g1_al, g1_ar, g1_b);

    // 4) gat2 linear (XCD-swizzled): h2h fp16 = h1x(fp16) @ g2_W^T
    gemm_h8<0, false, true, false, true><<<dim3(2, 512, 1), blkG, 0, stream>>>(
        H1X, G2W, NUL, h2h, 512, 512, 256, 0);

    // 5) gat2 attention + pool + layernorm: h2h fp16 -> normed fp16
    gat2_attn_kernel<<<dim3(4096), blk, 0, stream>>>(
        h2h, miss, g2_al, g2_ar, g2_b, ln_g, ln_b, normed);

    // 6) head1: hid fp32 = relu(normed(fp16) @ h_W1^T + h_b1)
    gemm_h8<1, false, false, true, false><<<dim3(2, 128, 1), blkG, 0, stream>>>(
        N4, HW1, HB1, hid, 256, 256, 256, 0);

    // 7) head2: out[16384,8]
    head2_kernel<<<dim3(512), blk, 0, stream>>>(hid, h_W2, h_b2, out);
}

// Round 26
// 325.418 us; speedup vs baseline: 2.7607x; 2.7607x over previous
//
#include <hip/hip_runtime.h>

// B=16384, FEAT=1024, FD=256, M=4 nodes, H1=4x128 (concat->512), H2=1x256, OUT=8.
// Round 26 = r24 verbatim resubmit (best passing, 323.7us). r25's 3-ahead
// prefetch spilled to scratch (VGPR 52->36, 1GB scratch writes, 898us) and is
// reverted. Final configuration: fp16-MFMA GEMMs (8 waves, dbuf LDS, 1-ahead
// prefetch, XCD swizzle), full fp16 intermediates (validated at the 0.0078125
// floor), VALU-dieted attention, fused pool+LN.

typedef __attribute__((ext_vector_type(8))) _Float16 f16x8;
typedef __attribute__((ext_vector_type(4))) float f32x4;

struct P4 { const void* p[4]; };

#define SYM(i,j) ((i)*(7-(i))/2 + (j))

__device__ __forceinline__ float sigmoidf_(float x) { return 1.0f / (1.0f + __expf(-x)); }
__device__ __forceinline__ float gelu_(float x) {
    return 0.5f * x * (1.0f + erff(x * 0.70710678118654752440f));
}

// ---- MFMA NT GEMM, 512 threads = 8 waves (2 row x 4 col), BM=BN=128, BK=32 --
// A fp32 (cvt at ds_write) or fp16 (direct); W fp32 (cvt at ds_write);
// C fp32 (scattered) or fp16 (LDS-transpose epilogue). SWZ: XCD chunked remap.
template<int ACT, bool A_F32, bool OUT_F16, bool HAS_BIAS, bool SWZ>
__global__ __launch_bounds__(512)
void gemm_h8(P4 A4, P4 W4, P4 b4, void* __restrict__ Cv,
             int K, int lda, int ldc, int zofs)
{
    __shared__ __align__(16) unsigned char smem[32768];
    _Float16 (*As)[128][32] = (_Float16(*)[128][32])smem;            // [2][128][32]
    _Float16 (*Bs)[128][32] = (_Float16(*)[128][32])(smem + 16384);  // [2][128][32]
    _Float16 (*outT)[128]   = (_Float16(*)[128])smem;                // [128][128] alias

    const int z = blockIdx.z;
    const float* __restrict__ bias = (const float*)b4.p[z];
    const float* __restrict__ Bw   = (const float*)W4.p[z];

    int bx = blockIdx.x, by = blockIdx.y;
    if constexpr (SWZ) {
        const int nxy  = gridDim.x * gridDim.y;
        const int flat = by * gridDim.x + bx;
        const int chunk = nxy >> 3;
        const int swz = (flat & 7) * chunk + (flat >> 3);
        bx = swz % gridDim.x;
        by = swz / gridDim.x;
    }

    const int t    = threadIdx.x;
    const int lane = t & 63;
    const int w    = t >> 6;
    const int wr   = (w >> 2) << 6;
    const int wc   = (w & 3) << 5;
    const long rowA = (long)by * 128;
    const long colB = (long)bx * 128;

    const float* Bpt[2];
    int brr[2], bcc[2];
    #pragma unroll
    for (int i = 0; i < 2; ++i) {
        const int f = t + i * 512;
        brr[i] = f >> 3;
        bcc[i] = (f & 7) << 2;
        Bpt[i] = Bw + (colB + brr[i]) * (long)K + bcc[i];
    }
    const float* Apt32[2]; int arr[2], acc_[2];
    const _Float16* Apt16 = nullptr; int a16r = 0, a16c = 0;
    if constexpr (A_F32) {
        const float* A = (const float*)A4.p[z];
        #pragma unroll
        for (int i = 0; i < 2; ++i) {
            const int f = t + i * 512;
            arr[i] = f >> 3;
            acc_[i] = (f & 7) << 2;
            Apt32[i] = A + (rowA + arr[i]) * (long)lda + acc_[i];
        }
    } else {
        const _Float16* A = (const _Float16*)A4.p[z];
        a16r = t >> 2;
        a16c = (t & 3) << 3;
        Apt16 = A + (rowA + a16r) * (long)lda + a16c;
    }

    f32x4 acc[4][2] = {};
    const int NK = K >> 5;

    float4 aP32[2], aN32[2], bP[2], bN[2];
    uint4  aP16 = {}, aN16 = {};

    if constexpr (A_F32) {
        #pragma unroll
        for (int i = 0; i < 2; ++i) aP32[i] = *(const float4*)(Apt32[i]);
    } else {
        aP16 = *(const uint4*)(Apt16);
    }
    #pragma unroll
    for (int i = 0; i < 2; ++i) bP[i] = *(const float4*)(Bpt[i]);

    if constexpr (A_F32) {
        #pragma unroll
        for (int i = 0; i < 2; ++i) {
            union { _Float16 h[4]; uint2 u; } pa;
            pa.h[0] = (_Float16)aP32[i].x; pa.h[1] = (_Float16)aP32[i].y;
            pa.h[2] = (_Float16)aP32[i].z; pa.h[3] = (_Float16)aP32[i].w;
            *(uint2*)&As[0][arr[i]][acc_[i]] = pa.u;
        }
    } else {
        *(uint4*)&As[0][a16r][a16c] = aP16;
    }
    #pragma unroll
    for (int i = 0; i < 2; ++i) {
        union { _Float16 h[4]; uint2 u; } pb;
        pb.h[0] = (_Float16)bP[i].x; pb.h[1] = (_Float16)bP[i].y;
        pb.h[2] = (_Float16)bP[i].z; pb.h[3] = (_Float16)bP[i].w;
        *(uint2*)&Bs[0][brr[i]][bcc[i]] = pb.u;
    }
    if (NK > 1) {
        if constexpr (A_F32) {
            #pragma unroll
            for (int i = 0; i < 2; ++i) aP32[i] = *(const float4*)(Apt32[i] + 32);
        } else {
            aP16 = *(const uint4*)(Apt16 + 32);
        }
        #pragma unroll
        for (int i = 0; i < 2; ++i) bP[i] = *(const float4*)(Bpt[i] + 32);
    }
    __syncthreads();

    const int fr = lane & 15;
    const int fq = lane >> 4;
    const int fg = fq << 3;

    for (int kk = 0; kk < NK; ++kk) {
        const int cur = kk & 1, nxt = cur ^ 1;

        if (kk + 1 < NK) {
            if constexpr (A_F32) {
                #pragma unroll
                for (int i = 0; i < 2; ++i) {
                    union { _Float16 h[4]; uint2 u; } pa;
                    pa.h[0] = (_Float16)aP32[i].x; pa.h[1] = (_Float16)aP32[i].y;
                    pa.h[2] = (_Float16)aP32[i].z; pa.h[3] = (_Float16)aP32[i].w;
                    *(uint2*)&As[nxt][arr[i]][acc_[i]] = pa.u;
                }
            } else {
                *(uint4*)&As[nxt][a16r][a16c] = aP16;
            }
            #pragma unroll
            for (int i = 0; i < 2; ++i) {
                union { _Float16 h[4]; uint2 u; } pb;
                pb.h[0] = (_Float16)bP[i].x; pb.h[1] = (_Float16)bP[i].y;
                pb.h[2] = (_Float16)bP[i].z; pb.h[3] = (_Float16)bP[i].w;
                *(uint2*)&Bs[nxt][brr[i]][bcc[i]] = pb.u;
            }
        }

        if (kk + 2 < NK) {
            const int ko = (kk + 2) << 5;
            if constexpr (A_F32) {
                #pragma unroll
                for (int i = 0; i < 2; ++i) aN32[i] = *(const float4*)(Apt32[i] + ko);
            } else {
                aN16 = *(const uint4*)(Apt16 + ko);
            }
            #pragma unroll
            for (int i = 0; i < 2; ++i) bN[i] = *(const float4*)(Bpt[i] + ko);
        }

        f16x8 af[4], bf[2];
        #pragma unroll
        for (int m = 0; m < 4; ++m) af[m] = *(const f16x8*)&As[cur][wr + m*16 + fr][fg];
        #pragma unroll
        for (int n = 0; n < 2; ++n) bf[n] = *(const f16x8*)&Bs[cur][wc + n*16 + fr][fg];
        #pragma unroll
        for (int m = 0; m < 4; ++m)
            #pragma unroll
            for (int n = 0; n < 2; ++n)
                acc[m][n] = __builtin_amdgcn_mfma_f32_16x16x32_f16(af[m], bf[n], acc[m][n], 0, 0, 0);

        __syncthreads();
        if (kk + 2 < NK) {
            if constexpr (A_F32) {
                #pragma unroll
                for (int i = 0; i < 2; ++i) aP32[i] = aN32[i];
            } else {
                aP16 = aN16;
            }
            #pragma unroll
            for (int i = 0; i < 2; ++i) bP[i] = bN[i];
        }
    }

    if constexpr (OUT_F16) {
        _Float16* Cz = (_Float16*)Cv + (long)z * zofs;
        __syncthreads();
        float bn[2];
        #pragma unroll
        for (int n = 0; n < 2; ++n)
            bn[n] = HAS_BIAS ? bias[colB + wc + n*16 + fr] : 0.0f;
        #pragma unroll
        for (int m = 0; m < 4; ++m)
            #pragma unroll
            for (int n = 0; n < 2; ++n)
                #pragma unroll
                for (int j = 0; j < 4; ++j) {
                    float x = acc[m][n][j] + bn[n];
                    if (ACT == 1) x = fmaxf(x, 0.0f);
                    outT[wr + m*16 + fq*4 + j][wc + n*16 + fr] = (_Float16)x;
                }
        __syncthreads();
        #pragma unroll
        for (int i = 0; i < 4; ++i) {
            const int s = t + i * 512;
            const int r = s >> 4, c = (s & 15) << 3;
            *(uint4*)(Cz + (rowA + r) * (long)ldc + colB + c) = *(const uint4*)&outT[r][c];
        }
    } else {
        float* Cz = (float*)Cv + (long)z * zofs;
        #pragma unroll
        for (int n = 0; n < 2; ++n) {
            const long col = colB + wc + n*16 + fr;
            const float bn = HAS_BIAS ? bias[col] : 0.0f;
            #pragma unroll
            for (int m = 0; m < 4; ++m) {
                const long row0 = rowA + wr + m*16 + fq*4;
                #pragma unroll
                for (int j = 0; j < 4; ++j) {
                    float x = acc[m][n][j] + bn;
                    if (ACT == 1) x = fmaxf(x, 0.0f);
                    Cz[(row0 + j) * (long)ldc + col] = x;
                }
            }
        }
    }
}

// -- GAT1 attention: fp16 in, fp32 compute, fp16 out --------------------------
__global__ __launch_bounds__(256)
void gat1_attn_kernel(const _Float16* __restrict__ h1f,
                      _Float16* __restrict__ h1x,
                      const int* __restrict__ missing,
                      const float* __restrict__ attl, const float* __restrict__ attr,
                      const float* __restrict__ bias)
{
    const int gtid = blockIdx.x * 256 + threadIdx.x;
    const int wid  = gtid >> 6;
    const int lane = threadIdx.x & 63;
    const int b = wid >> 2;
    const int h = wid & 3;
    const int cb = h * 128 + lane;
    const _Float16* bi = h1f + (size_t)b * 2048 + cb;
    _Float16*       bo = h1x + (size_t)b * 2048 + cb;

    float hr[4][2];
    #pragma unroll
    for (int j = 0; j < 4; ++j) {
        hr[j][0] = (float)bi[j*512];
        hr[j][1] = (float)bi[j*512 + 64];
    }
    const float al0 = attl[cb], al1 = attl[cb+64];
    const float ar0 = attr[cb], ar1 = attr[cb+64];

    float red[18];
    #pragma unroll
    for (int i = 0; i < 4; ++i)
        #pragma unroll
        for (int j = i; j < 4; ++j)
            red[SYM(i,j)] = hr[i][0]*hr[j][0] + hr[i][1]*hr[j][1];
    #pragma unroll
    for (int j = 0; j < 4; ++j) {
        red[10+j] = hr[j][0]*al0 + hr[j][1]*al1;
        red[14+j] = hr[j][0]*ar0 + hr[j][1]*ar1;
    }
    #pragma unroll
    for (int m = 1; m < 64; m <<= 1)
        #pragma unroll
        for (int r = 0; r < 18; ++r)
            red[r] += __shfl_xor(red[r], m, 64);

    const int miss = missing[b];
    bool pres[4];
    #pragma unroll
    for (int mm = 0; mm < 4; ++mm) pres[mm] = (miss != mm + 1);

    float attn[4][4];
    #pragma unroll
    for (int i = 0; i < 4; ++i) {
        float av[4]; float mx = -3.4e38f;
        #pragma unroll
        for (int j = 0; j < 4; ++j) {
            const bool mk = (i == j) || (pres[i] && pres[j]);
            const float l = (i <= j) ? red[SYM(i,j)] : red[SYM(j,i)];
            float v = (red[14+i] + red[10+j]) * sigmoidf_(l);
            v = (v >= 0.0f) ? v : 0.2f * v;
            av[j] = mk ? v : -1e30f;
            mx = fmaxf(mx, av[j]);
        }
        float den = 0.0f;
        #pragma unroll
        for (int j = 0; j < 4; ++j) { av[j] = __expf(av[j] - mx); den += av[j]; }
        const float inv = 1.0f / den;
        #pragma unroll
        for (int j = 0; j < 4; ++j) attn[i][j] = av[j] * inv;
    }

    const float b0 = bias[cb], b1 = bias[cb+64];
    #pragma unroll
    for (int i = 0; i < 4; ++i) {
        float o0 = b0, o1 = b1;
        #pragma unroll
        for (int j = 0; j < 4; ++j) { o0 += attn[i][j]*hr[j][0]; o1 += attn[i][j]*hr[j][1]; }
        bo[i*512]      = (_Float16)gelu_(o0);
        bo[i*512 + 64] = (_Float16)gelu_(o1);
    }
}

// ------- GAT2 attention + pool + LayerNorm: fp16 in, fp16 out ----------------
__global__ __launch_bounds__(256)
void gat2_attn_kernel(const _Float16* __restrict__ h2h,
                      const int* __restrict__ missing,
                      const float* __restrict__ attl, const float* __restrict__ attr,
                      const float* __restrict__ bias,
                      const float* __restrict__ lng, const float* __restrict__ lnb,
                      _Float16* __restrict__ normed)
{
    const int gtid = blockIdx.x * 256 + threadIdx.x;
    const int b = gtid >> 6;
    const int lane = threadIdx.x & 63;
    const _Float16* hp = h2h + (size_t)b * 1024;

    float4 hr[4];
    #pragma unroll
    for (int j = 0; j < 4; ++j) {
        union { uint2 u; _Float16 h[4]; } v;
        v.u = *(const uint2*)(hp + j * 256 + lane * 4);
        hr[j].x = (float)v.h[0]; hr[j].y = (float)v.h[1];
        hr[j].z = (float)v.h[2]; hr[j].w = (float)v.h[3];
    }
    const float4 al = ((const float4*)attl)[lane];
    const float4 ar = ((const float4*)attr)[lane];

    float red[18];
    #pragma unroll
    for (int i = 0; i < 4; ++i)
        #pragma unroll
        for (int j = i; j < 4; ++j)
            red[SYM(i,j)] = hr[i].x*hr[j].x + hr[i].y*hr[j].y + hr[i].z*hr[j].z + hr[i].w*hr[j].w;
    #pragma unroll
    for (int j = 0; j < 4; ++j) {
        red[10+j] = hr[j].x*al.x + hr[j].y*al.y + hr[j].z*al.z + hr[j].w*al.w;
        red[14+j] = hr[j].x*ar.x + hr[j].y*ar.y + hr[j].z*ar.z + hr[j].w*ar.w;
    }
    #pragma unroll
    for (int m = 1; m < 64; m <<= 1)
        #pragma unroll
        for (int r = 0; r < 18; ++r)
            red[r] += __shfl_xor(red[r], m, 64);

    const int miss = missing[b];
    bool pres[4];
    #pragma unroll
    for (int mm = 0; mm < 4; ++mm) pres[mm] = (miss != mm + 1);

    float wsum[4] = {0.f, 0.f, 0.f, 0.f};
    #pragma unroll
    for (int i = 0; i < 4; ++i) {
        float av[4]; float mx = -3.4e38f;
        #pragma unroll
        for (int j = 0; j < 4; ++j) {
            const bool mk = (i == j) || (pres[i] && pres[j]);
            const float l = (i <= j) ? red[SYM(i,j)] : red[SYM(j,i)];
            float v = (red[14+i] + red[10+j]) * sigmoidf_(l);
            v = (v >= 0.0f) ? v : 0.2f * v;
            av[j] = mk ? v : -1e30f;
            mx = fmaxf(mx, av[j]);
        }
        float den = 0.0f;
        #pragma unroll
        for (int j = 0; j < 4; ++j) { av[j] = __expf(av[j] - mx); den += av[j]; }
        const float inv = 0.25f / den;
        #pragma unroll
        for (int j = 0; j < 4; ++j) wsum[j] += av[j] * inv;
    }

    const float4 bv = ((const float4*)bias)[lane];
    float pooled[4] = {bv.x, bv.y, bv.z, bv.w};
    #pragma unroll
    for (int j = 0; j < 4; ++j) {
        pooled[0] += wsum[j] * hr[j].x;
        pooled[1] += wsum[j] * hr[j].y;
        pooled[2] += wsum[j] * hr[j].z;
        pooled[3] += wsum[j] * hr[j].w;
    }

    float s1 = pooled[0] + pooled[1] + pooled[2] + pooled[3];
    float s2 = pooled[0]*pooled[0] + pooled[1]*pooled[1] + pooled[2]*pooled[2] + pooled[3]*pooled[3];
    #pragma unroll
    for (int m = 1; m < 64; m <<= 1) {
        s1 += __shfl_xor(s1, m, 64);
        s2 += __shfl_xor(s2, m, 64);
    }
    const float mu   = s1 * (1.0f / 256.0f);
    const float var  = s2 * (1.0f / 256.0f) - mu * mu;
    const float rstd = rsqrtf(var + 1e-5f);
    const float4 g  = ((const float4*)lng)[lane];
    const float4 bb = ((const float4*)lnb)[lane];
    union { _Float16 h[4]; uint2 u; } o;
    o.h[0] = (_Float16)((pooled[0] - mu) * rstd * g.x + bb.x);
    o.h[1] = (_Float16)((pooled[1] - mu) * rstd * g.y + bb.y);
    o.h[2] = (_Float16)((pooled[2] - mu) * rstd * g.z + bb.z);
    o.h[3] = (_Float16)((pooled[3] - mu) * rstd * g.w + bb.w);
    *(uint2*)(normed + (size_t)b * 256 + lane * 4) = o.u;
}

// ---------------- head2: fp32 hid -------------------------------------------
__global__ __launch_bounds__(256)
void head2_kernel(const float* __restrict__ hid, const float* __restrict__ W2,
                  const float* __restrict__ b2, float* __restrict__ out)
{
    const int t = blockIdx.x * 256 + threadIdx.x;
    const int b = t >> 3, o = t & 7;
    const float4* hp = (const float4*)(hid + (size_t)b * 256);
    const float4* wp = (const float4*)(W2 + o * 256);
    float acc = b2[o];
    #pragma unroll 8
    for (int c = 0; c < 64; ++c) {
        const float4 hv = hp[c], wv = wp[c];
        acc += hv.x*wv.x + hv.y*wv.y + hv.z*wv.z + hv.w*wv.w;
    }
    out[t] = acc;
}

// ---------------- launch ----------------------------------------------------
extern "C" void kernel_launch(void* const* d_in, const int* in_sizes, int n_in,
                              void* d_out, int out_size, void* d_ws, size_t ws_size,
                              hipStream_t stream)
{
    (void)in_sizes; (void)n_in; (void)out_size; (void)ws_size;
    const int*   miss  = (const int*)d_in[4];
    const float* g1_al = (const float*)d_in[14];
    const float* g1_ar = (const float*)d_in[15];
    const float* g1_b  = (const float*)d_in[16];
    const float* g2_al = (const float*)d_in[18];
    const float* g2_ar = (const float*)d_in[19];
    const float* g2_b  = (const float*)d_in[20];
    const float* ln_g  = (const float*)d_in[21];
    const float* ln_b  = (const float*)d_in[22];
    const float* h_W2  = (const float*)d_in[25];
    const float* h_b2  = (const float*)d_in[26];
    float* out = (float*)d_out;

    // workspace (MiB offsets; peak 160 MiB):
    //   feats  fp16 [16384,1024] @   0  (32)  -> dead after gat1-lin
    //   h1f    fp16 [65536,512]  @  64  (64)  -> dead after gat1_attn
    //   h1x    fp16 [65536,512]  @   0  (64)  (overwrites dead feats)
    //   h2h    fp16 [65536,256]  @ 128  (32)
    //   normed fp16 [16384,256]  @  64  (8)   (overwrites dead h1f)
    //   hid    fp32 [16384,256]  @  80  (16)
    char* base = (char*)d_ws;
    _Float16* feats  = (_Float16*)base;
    _Float16* h1f    = (_Float16*)(base + (64ll  << 20));
    _Float16* h1x    = (_Float16*)base;
    _Float16* h2h    = (_Float16*)(base + (128ll << 20));
    _Float16* normed = (_Float16*)(base + (64ll  << 20));
    float*    hid    = (float*)   (base + (80ll  << 20));

    const dim3 blkG(512);
    const dim3 blk(256);

    P4 Xs  = {{d_in[0], d_in[1], d_in[2], d_in[3]}};
    P4 Wms = {{d_in[5], d_in[7], d_in[9], d_in[11]}};
    P4 bms = {{d_in[6], d_in[8], d_in[10], d_in[12]}};
    P4 F4  = {{feats, feats, feats, feats}};
    P4 G1W = {{d_in[13], d_in[13], d_in[13], d_in[13]}};
    P4 H1X = {{h1x, h1x, h1x, h1x}};
    P4 G2W = {{d_in[17], d_in[17], d_in[17], d_in[17]}};
    P4 N4  = {{normed, normed, normed, normed}};
    P4 HW1 = {{d_in[23], d_in[23], d_in[23], d_in[23]}};
    P4 HB1 = {{d_in[24], d_in[24], d_in[24], d_in[24]}};
    P4 NUL = {{nullptr, nullptr, nullptr, nullptr}};

    // 1) projections (z-batched, XCD-swizzled): feats fp16
    gemm_h8<0, true, true, true, true><<<dim3(2, 128, 4), blkG, 0, stream>>>(
        Xs, Wms, bms, feats, /*K=*/1024, /*lda=*/1024, /*ldc=*/1024, /*zofs=*/256);

    // 2) gat1 linear (XCD-swizzled): h1f fp16 = feats(fp16) @ g1_W^T
    gemm_h8<0, false, true, false, true><<<dim3(4, 512, 1), blkG, 0, stream>>>(
        F4, G1W, NUL, h1f, 256, 256, 512, 0);

    // 3) gat1 attention + bias + gelu: h1f fp16 -> h1x fp16
    gat1_attn_kernel<<<dim3(16384), blk, 0, stream>>>(
        h1f, h1x, miss, g1_al, g1_ar, g1_b);

    // 4) gat2 linear (XCD-swizzled): h2h fp16 = h1x(fp16) @ g2_W^T
    gemm_h8<0, false, true, false, true><<<dim3(2, 512, 1), blkG, 0, stream>>>(
        H1X, G2W, NUL, h2h, 512, 512, 256, 0);

    // 5) gat2 attention + pool + layernorm: h2h fp16 -> normed fp16
    gat2_attn_kernel<<<dim3(4096), blk, 0, stream>>>(
        h2h, miss, g2_al, g2_ar, g2_b, ln_g, ln_b, normed);

    // 6) head1: hid fp32 = relu(normed(fp16) @ h_W1^T + h_b1)
    gemm_h8<1, false, false, true, false><<<dim3(2, 128, 1), blkG, 0, stream>>>(
        N4, HW1, HB1, hid, 256, 256, 256, 0);

    // 7) head2: out[16384,8]
    head2_kernel<<<dim3(512), blk, 0, stream>>>(hid, h_W2, h_b2, out);
}

// Round 27
// 324.844 us; speedup vs baseline: 2.7656x; 1.0018x over previous
//
#include <hip/hip_runtime.h>

// B=16384, FEAT=1024, FD=256, M=4 nodes, H1=4x128 (concat->512), H2=1x256, OUT=8.
// FINAL (r24/r26 configuration, best passing: 323.7us, 3.84x over baseline).
// fp16-MFMA GEMMs (8 waves, dbuf LDS, 1-ahead prefetch, XCD swizzle on >L3
// inputs), full fp16 intermediate chain (validated at the 0.0078125 absmax
// floor), VALU-dieted standalone attention, fused pool+LayerNorm.

typedef __attribute__((ext_vector_type(8))) _Float16 f16x8;
typedef __attribute__((ext_vector_type(4))) float f32x4;

struct P4 { const void* p[4]; };

#define SYM(i,j) ((i)*(7-(i))/2 + (j))

__device__ __forceinline__ float sigmoidf_(float x) { return 1.0f / (1.0f + __expf(-x)); }
__device__ __forceinline__ float gelu_(float x) {
    return 0.5f * x * (1.0f + erff(x * 0.70710678118654752440f));
}

// ---- MFMA NT GEMM, 512 threads = 8 waves (2 row x 4 col), BM=BN=128, BK=32 --
// A fp32 (cvt at ds_write) or fp16 (direct); W fp32 (cvt at ds_write);
// C fp32 (scattered) or fp16 (LDS-transpose epilogue). SWZ: XCD chunked remap.
template<int ACT, bool A_F32, bool OUT_F16, bool HAS_BIAS, bool SWZ>
__global__ __launch_bounds__(512)
void gemm_h8(P4 A4, P4 W4, P4 b4, void* __restrict__ Cv,
             int K, int lda, int ldc, int zofs)
{
    __shared__ __align__(16) unsigned char smem[32768];
    _Float16 (*As)[128][32] = (_Float16(*)[128][32])smem;            // [2][128][32]
    _Float16 (*Bs)[128][32] = (_Float16(*)[128][32])(smem + 16384);  // [2][128][32]
    _Float16 (*outT)[128]   = (_Float16(*)[128])smem;                // [128][128] alias

    const int z = blockIdx.z;
    const float* __restrict__ bias = (const float*)b4.p[z];
    const float* __restrict__ Bw   = (const float*)W4.p[z];

    int bx = blockIdx.x, by = blockIdx.y;
    if constexpr (SWZ) {
        const int nxy  = gridDim.x * gridDim.y;
        const int flat = by * gridDim.x + bx;
        const int chunk = nxy >> 3;
        const int swz = (flat & 7) * chunk + (flat >> 3);
        bx = swz % gridDim.x;
        by = swz / gridDim.x;
    }

    const int t    = threadIdx.x;
    const int lane = t & 63;
    const int w    = t >> 6;
    const int wr   = (w >> 2) << 6;
    const int wc   = (w & 3) << 5;
    const long rowA = (long)by * 128;
    const long colB = (long)bx * 128;

    const float* Bpt[2];
    int brr[2], bcc[2];
    #pragma unroll
    for (int i = 0; i < 2; ++i) {
        const int f = t + i * 512;
        brr[i] = f >> 3;
        bcc[i] = (f & 7) << 2;
        Bpt[i] = Bw + (colB + brr[i]) * (long)K + bcc[i];
    }
    const float* Apt32[2]; int arr[2], acc_[2];
    const _Float16* Apt16 = nullptr; int a16r = 0, a16c = 0;
    if constexpr (A_F32) {
        const float* A = (const float*)A4.p[z];
        #pragma unroll
        for (int i = 0; i < 2; ++i) {
            const int f = t + i * 512;
            arr[i] = f >> 3;
            acc_[i] = (f & 7) << 2;
            Apt32[i] = A + (rowA + arr[i]) * (long)lda + acc_[i];
        }
    } else {
        const _Float16* A = (const _Float16*)A4.p[z];
        a16r = t >> 2;
        a16c = (t & 3) << 3;
        Apt16 = A + (rowA + a16r) * (long)lda + a16c;
    }

    f32x4 acc[4][2] = {};
    const int NK = K >> 5;

    float4 aP32[2], aN32[2], bP[2], bN[2];
    uint4  aP16 = {}, aN16 = {};

    if constexpr (A_F32) {
        #pragma unroll
        for (int i = 0; i < 2; ++i) aP32[i] = *(const float4*)(Apt32[i]);
    } else {
        aP16 = *(const uint4*)(Apt16);
    }
    #pragma unroll
    for (int i = 0; i < 2; ++i) bP[i] = *(const float4*)(Bpt[i]);

    if constexpr (A_F32) {
        #pragma unroll
        for (int i = 0; i < 2; ++i) {
            union { _Float16 h[4]; uint2 u; } pa;
            pa.h[0] = (_Float16)aP32[i].x; pa.h[1] = (_Float16)aP32[i].y;
            pa.h[2] = (_Float16)aP32[i].z; pa.h[3] = (_Float16)aP32[i].w;
            *(uint2*)&As[0][arr[i]][acc_[i]] = pa.u;
        }
    } else {
        *(uint4*)&As[0][a16r][a16c] = aP16;
    }
    #pragma unroll
    for (int i = 0; i < 2; ++i) {
        union { _Float16 h[4]; uint2 u; } pb;
        pb.h[0] = (_Float16)bP[i].x; pb.h[1] = (_Float16)bP[i].y;
        pb.h[2] = (_Float16)bP[i].z; pb.h[3] = (_Float16)bP[i].w;
        *(uint2*)&Bs[0][brr[i]][bcc[i]] = pb.u;
    }
    if (NK > 1) {
        if constexpr (A_F32) {
            #pragma unroll
            for (int i = 0; i < 2; ++i) aP32[i] = *(const float4*)(Apt32[i] + 32);
        } else {
            aP16 = *(const uint4*)(Apt16 + 32);
        }
        #pragma unroll
        for (int i = 0; i < 2; ++i) bP[i] = *(const float4*)(Bpt[i] + 32);
    }
    __syncthreads();

    const int fr = lane & 15;
    const int fq = lane >> 4;
    const int fg = fq << 3;

    for (int kk = 0; kk < NK; ++kk) {
        const int cur = kk & 1, nxt = cur ^ 1;

        if (kk + 1 < NK) {
            if constexpr (A_F32) {
                #pragma unroll
                for (int i = 0; i < 2; ++i) {
                    union { _Float16 h[4]; uint2 u; } pa;
                    pa.h[0] = (_Float16)aP32[i].x; pa.h[1] = (_Float16)aP32[i].y;
                    pa.h[2] = (_Float16)aP32[i].z; pa.h[3] = (_Float16)aP32[i].w;
                    *(uint2*)&As[nxt][arr[i]][acc_[i]] = pa.u;
                }
            } else {
                *(uint4*)&As[nxt][a16r][a16c] = aP16;
            }
            #pragma unroll
            for (int i = 0; i < 2; ++i) {
                union { _Float16 h[4]; uint2 u; } pb;
                pb.h[0] = (_Float16)bP[i].x; pb.h[1] = (_Float16)bP[i].y;
                pb.h[2] = (_Float16)bP[i].z; pb.h[3] = (_Float16)bP[i].w;
                *(uint2*)&Bs[nxt][brr[i]][bcc[i]] = pb.u;
            }
        }

        if (kk + 2 < NK) {
            const int ko = (kk + 2) << 5;
            if constexpr (A_F32) {
                #pragma unroll
                for (int i = 0; i < 2; ++i) aN32[i] = *(const float4*)(Apt32[i] + ko);
            } else {
                aN16 = *(const uint4*)(Apt16 + ko);
            }
            #pragma unroll
            for (int i = 0; i < 2; ++i) bN[i] = *(const float4*)(Bpt[i] + ko);
        }

        f16x8 af[4], bf[2];
        #pragma unroll
        for (int m = 0; m < 4; ++m) af[m] = *(const f16x8*)&As[cur][wr + m*16 + fr][fg];
        #pragma unroll
        for (int n = 0; n < 2; ++n) bf[n] = *(const f16x8*)&Bs[cur][wc + n*16 + fr][fg];
        #pragma unroll
        for (int m = 0; m < 4; ++m)
            #pragma unroll
            for (int n = 0; n < 2; ++n)
                acc[m][n] = __builtin_amdgcn_mfma_f32_16x16x32_f16(af[m], bf[n], acc[m][n], 0, 0, 0);

        __syncthreads();
        if (kk + 2 < NK) {
            if constexpr (A_F32) {
                #pragma unroll
                for (int i = 0; i < 2; ++i) aP32[i] = aN32[i];
            } else {
                aP16 = aN16;
            }
            #pragma unroll
            for (int i = 0; i < 2; ++i) bP[i] = bN[i];
        }
    }

    if constexpr (OUT_F16) {
        _Float16* Cz = (_Float16*)Cv + (long)z * zofs;
        __syncthreads();
        float bn[2];
        #pragma unroll
        for (int n = 0; n < 2; ++n)
            bn[n] = HAS_BIAS ? bias[colB + wc + n*16 + fr] : 0.0f;
        #pragma unroll
        for (int m = 0; m < 4; ++m)
            #pragma unroll
            for (int n = 0; n < 2; ++n)
                #pragma unroll
                for (int j = 0; j < 4; ++j) {
                    float x = acc[m][n][j] + bn[n];
                    if (ACT == 1) x = fmaxf(x, 0.0f);
                    outT[wr + m*16 + fq*4 + j][wc + n*16 + fr] = (_Float16)x;
                }
        __syncthreads();
        #pragma unroll
        for (int i = 0; i < 4; ++i) {
            const int s = t + i * 512;
            const int r = s >> 4, c = (s & 15) << 3;
            *(uint4*)(Cz + (rowA + r) * (long)ldc + colB + c) = *(const uint4*)&outT[r][c];
        }
    } else {
        float* Cz = (float*)Cv + (long)z * zofs;
        #pragma unroll
        for (int n = 0; n < 2; ++n) {
            const long col = colB + wc + n*16 + fr;
            const float bn = HAS_BIAS ? bias[col] : 0.0f;
            #pragma unroll
            for (int m = 0; m < 4; ++m) {
                const long row0 = rowA + wr + m*16 + fq*4;
                #pragma unroll
                for (int j = 0; j < 4; ++j) {
                    float x = acc[m][n][j] + bn;
                    if (ACT == 1) x = fmaxf(x, 0.0f);
                    Cz[(row0 + j) * (long)ldc + col] = x;
                }
            }
        }
    }
}

// -- GAT1 attention: fp16 in, fp32 compute, fp16 out --------------------------
__global__ __launch_bounds__(256)
void gat1_attn_kernel(const _Float16* __restrict__ h1f,
                      _Float16* __restrict__ h1x,
                      const int* __restrict__ missing,
                      const float* __restrict__ attl, const float* __restrict__ attr,
                      const float* __restrict__ bias)
{
    const int gtid = blockIdx.x * 256 + threadIdx.x;
    const int wid  = gtid >> 6;
    const int lane = threadIdx.x & 63;
    const int b = wid >> 2;
    const int h = wid & 3;
    const int cb = h * 128 + lane;
    const _Float16* bi = h1f + (size_t)b * 2048 + cb;
    _Float16*       bo = h1x + (size_t)b * 2048 + cb;

    float hr[4][2];
    #pragma unroll
    for (int j = 0; j < 4; ++j) {
        hr[j][0] = (float)bi[j*512];
        hr[j][1] = (float)bi[j*512 + 64];
    }
    const float al0 = attl[cb], al1 = attl[cb+64];
    const float ar0 = attr[cb], ar1 = attr[cb+64];

    float red[18];
    #pragma unroll
    for (int i = 0; i < 4; ++i)
        #pragma unroll
        for (int j = i; j < 4; ++j)
            red[SYM(i,j)] = hr[i][0]*hr[j][0] + hr[i][1]*hr[j][1];
    #pragma unroll
    for (int j = 0; j < 4; ++j) {
        red[10+j] = hr[j][0]*al0 + hr[j][1]*al1;
        red[14+j] = hr[j][0]*ar0 + hr[j][1]*ar1;
    }
    #pragma unroll
    for (int m = 1; m < 64; m <<= 1)
        #pragma unroll
        for (int r = 0; r < 18; ++r)
            red[r] += __shfl_xor(red[r], m, 64);

    const int miss = missing[b];
    bool pres[4];
    #pragma unroll
    for (int mm = 0; mm < 4; ++mm) pres[mm] = (miss != mm + 1);

    float attn[4][4];
    #pragma unroll
    for (int i = 0; i < 4; ++i) {
        float av[4]; float mx = -3.4e38f;
        #pragma unroll
        for (int j = 0; j < 4; ++j) {
            const bool mk = (i == j) || (pres[i] && pres[j]);
            const float l = (i <= j) ? red[SYM(i,j)] : red[SYM(j,i)];
            float v = (red[14+i] + red[10+j]) * sigmoidf_(l);
            v = (v >= 0.0f) ? v : 0.2f * v;
            av[j] = mk ? v : -1e30f;
            mx = fmaxf(mx, av[j]);
        }
        float den = 0.0f;
        #pragma unroll
        for (int j = 0; j < 4; ++j) { av[j] = __expf(av[j] - mx); den += av[j]; }
        const float inv = 1.0f / den;
        #pragma unroll
        for (int j = 0; j < 4; ++j) attn[i][j] = av[j] * inv;
    }

    const float b0 = bias[cb], b1 = bias[cb+64];
    #pragma unroll
    for (int i = 0; i < 4; ++i) {
        float o0 = b0, o1 = b1;
        #pragma unroll
        for (int j = 0; j < 4; ++j) { o0 += attn[i][j]*hr[j][0]; o1 += attn[i][j]*hr[j][1]; }
        bo[i*512]      = (_Float16)gelu_(o0);
        bo[i*512 + 64] = (_Float16)gelu_(o1);
    }
}

// ------- GAT2 attention + pool + LayerNorm: fp16 in, fp16 out ----------------
__global__ __launch_bounds__(256)
void gat2_attn_kernel(const _Float16* __restrict__ h2h,
                      const int* __restrict__ missing,
                      const float* __restrict__ attl, const float* __restrict__ attr,
                      const float* __restrict__ bias,
                      const float* __restrict__ lng, const float* __restrict__ lnb,
                      _Float16* __restrict__ normed)
{
    const int gtid = blockIdx.x * 256 + threadIdx.x;
    const int b = gtid >> 6;
    const int lane = threadIdx.x & 63;
    const _Float16* hp = h2h + (size_t)b * 1024;

    float4 hr[4];
    #pragma unroll
    for (int j = 0; j < 4; ++j) {
        union { uint2 u; _Float16 h[4]; } v;
        v.u = *(const uint2*)(hp + j * 256 + lane * 4);
        hr[j].x = (float)v.h[0]; hr[j].y = (float)v.h[1];
        hr[j].z = (float)v.h[2]; hr[j].w = (float)v.h[3];
    }
    const float4 al = ((const float4*)attl)[lane];
    const float4 ar = ((const float4*)attr)[lane];

    float red[18];
    #pragma unroll
    for (int i = 0; i < 4; ++i)
        #pragma unroll
        for (int j = i; j < 4; ++j)
            red[SYM(i,j)] = hr[i].x*hr[j].x + hr[i].y*hr[j].y + hr[i].z*hr[j].z + hr[i].w*hr[j].w;
    #pragma unroll
    for (int j = 0; j < 4; ++j) {
        red[10+j] = hr[j].x*al.x + hr[j].y*al.y + hr[j].z*al.z + hr[j].w*al.w;
        red[14+j] = hr[j].x*ar.x + hr[j].y*ar.y + hr[j].z*ar.z + hr[j].w*ar.w;
    }
    #pragma unroll
    for (int m = 1; m < 64; m <<= 1)
        #pragma unroll
        for (int r = 0; r < 18; ++r)
            red[r] += __shfl_xor(red[r], m, 64);

    const int miss = missing[b];
    bool pres[4];
    #pragma unroll
    for (int mm = 0; mm < 4; ++mm) pres[mm] = (miss != mm + 1);

    float wsum[4] = {0.f, 0.f, 0.f, 0.f};
    #pragma unroll
    for (int i = 0; i < 4; ++i) {
        float av[4]; float mx = -3.4e38f;
        #pragma unroll
        for (int j = 0; j < 4; ++j) {
            const bool mk = (i == j) || (pres[i] && pres[j]);
            const float l = (i <= j) ? red[SYM(i,j)] : red[SYM(j,i)];
            float v = (red[14+i] + red[10+j]) * sigmoidf_(l);
            v = (v >= 0.0f) ? v : 0.2f * v;
            av[j] = mk ? v : -1e30f;
            mx = fmaxf(mx, av[j]);
        }
        float den = 0.0f;
        #pragma unroll
        for (int j = 0; j < 4; ++j) { av[j] = __expf(av[j] - mx); den += av[j]; }
        const float inv = 0.25f / den;
        #pragma unroll
        for (int j = 0; j < 4; ++j) wsum[j] += av[j] * inv;
    }

    const float4 bv = ((const float4*)bias)[lane];
    float pooled[4] = {bv.x, bv.y, bv.z, bv.w};
    #pragma unroll
    for (int j = 0; j < 4; ++j) {
        pooled[0] += wsum[j] * hr[j].x;
        pooled[1] += wsum[j] * hr[j].y;
        pooled[2] += wsum[j] * hr[j].z;
        pooled[3] += wsum[j] * hr[j].w;
    }

    float s1 = pooled[0] + pooled[1] + pooled[2] + pooled[3];
    float s2 = pooled[0]*pooled[0] + pooled[1]*pooled[1] + pooled[2]*pooled[2] + pooled[3]*pooled[3];
    #pragma unroll
    for (int m = 1; m < 64; m <<= 1) {
        s1 += __shfl_xor(s1, m, 64);
        s2 += __shfl_xor(s2, m, 64);
    }
    const float mu   = s1 * (1.0f / 256.0f);
    const float var  = s2 * (1.0f / 256.0f) - mu * mu;
    const float rstd = rsqrtf(var + 1e-5f);
    const float4 g  = ((const float4*)lng)[lane];
    const float4 bb = ((const float4*)lnb)[lane];
    union { _Float16 h[4]; uint2 u; } o;
    o.h[0] = (_Float16)((pooled[0] - mu) * rstd * g.x + bb.x);
    o.h[1] = (_Float16)((pooled[1] - mu) * rstd * g.y + bb.y);
    o.h[2] = (_Float16)((pooled[2] - mu) * rstd * g.z + bb.z);
    o.h[3] = (_Float16)((pooled[3] - mu) * rstd * g.w + bb.w);
    *(uint2*)(normed + (size_t)b * 256 + lane * 4) = o.u;
}

// ---------------- head2: fp32 hid -------------------------------------------
__global__ __launch_bounds__(256)
void head2_kernel(const float* __restrict__ hid, const float* __restrict__ W2,
                  const float* __restrict__ b2, float* __restrict__ out)
{
    const int t = blockIdx.x * 256 + threadIdx.x;
    const int b = t >> 3, o = t & 7;
    const float4* hp = (const float4*)(hid + (size_t)b * 256);
    const float4* wp = (const float4*)(W2 + o * 256);
    float acc = b2[o];
    #pragma unroll 8
    for (int c = 0; c < 64; ++c) {
        const float4 hv = hp[c], wv = wp[c];
        acc += hv.x*wv.x + hv.y*wv.y + hv.z*wv.z + hv.w*wv.w;
    }
    out[t] = acc;
}

// ---------------- launch ----------------------------------------------------
extern "C" void kernel_launch(void* const* d_in, const int* in_sizes, int n_in,
                              void* d_out, int out_size, void* d_ws, size_t ws_size,
                              hipStream_t stream)
{
    (void)in_sizes; (void)n_in; (void)out_size; (void)ws_size;
    const int*   miss  = (const int*)d_in[4];
    const float* g1_al = (const float*)d_in[14];
    const float* g1_ar = (const float*)d_in[15];
    const float* g1_b  = (const float*)d_in[16];
    const float* g2_al = (const float*)d_in[18];
    const float* g2_ar = (const float*)d_in[19];
    const float* g2_b  = (const float*)d_in[20];
    const float* ln_g  = (const float*)d_in[21];
    const float* ln_b  = (const float*)d_in[22];
    const float* h_W2  = (const float*)d_in[25];
    const float* h_b2  = (const float*)d_in[26];
    float* out = (float*)d_out;

    // workspace (MiB offsets; peak 160 MiB):
    //   feats  fp16 [16384,1024] @   0  (32)  -> dead after gat1-lin
    //   h1f    fp16 [65536,512]  @  64  (64)  -> dead after gat1_attn
    //   h1x    fp16 [65536,512]  @   0  (64)  (overwrites dead feats)
    //   h2h    fp16 [65536,256]  @ 128  (32)
    //   normed fp16 [16384,256]  @  64  (8)   (overwrites dead h1f)
    //   hid    fp32 [16384,256]  @  80  (16)
    char* base = (char*)d_ws;
    _Float16* feats  = (_Float16*)base;
    _Float16* h1f    = (_Float16*)(base + (64ll  << 20));
    _Float16* h1x    = (_Float16*)base;
    _Float16* h2h    = (_Float16*)(base + (128ll << 20));
    _Float16* normed = (_Float16*)(base + (64ll  << 20));
    float*    hid    = (float*)   (base + (80ll  << 20));

    const dim3 blkG(512);
    const dim3 blk(256);

    P4 Xs  = {{d_in[0], d_in[1], d_in[2], d_in[3]}};
    P4 Wms = {{d_in[5], d_in[7], d_in[9], d_in[11]}};
    P4 bms = {{d_in[6], d_in[8], d_in[10], d_in[12]}};
    P4 F4  = {{feats, feats, feats, feats}};
    P4 G1W = {{d_in[13], d_in[13], d_in[13], d_in[13]}};
    P4 H1X = {{h1x, h1x, h1x, h1x}};
    P4 G2W = {{d_in[17], d_in[17], d_in[17], d_in[17]}};
    P4 N4  = {{normed, normed, normed, normed}};
    P4 HW1 = {{d_in[23], d_in[23], d_in[23], d_in[23]}};
    P4 HB1 = {{d_in[24], d_in[24], d_in[24], d_in[24]}};
    P4 NUL = {{nullptr, nullptr, nullptr, nullptr}};

    // 1) projections (z-batched, XCD-swizzled): feats fp16
    gemm_h8<0, true, true, true, true><<<dim3(2, 128, 4), blkG, 0, stream>>>(
        Xs, Wms, bms, feats, /*K=*/1024, /*lda=*/1024, /*ldc=*/1024, /*zofs=*/256);

    // 2) gat1 linear (XCD-swizzled): h1f fp16 = feats(fp16) @ g1_W^T
    gemm_h8<0, false, true, false, true><<<dim3(4, 512, 1), blkG, 0, stream>>>(
        F4, G1W, NUL, h1f, 256, 256, 512, 0);

    // 3) gat1 attention + bias + gelu: h1f fp16 -> h1x fp16
    gat1_attn_kernel<<<dim3(16384), blk, 0, stream>>>(
        h1f, h1x, miss, g1_al, g1_ar, g1_b);

    // 4) gat2 linear (XCD-swizzled): h2h fp16 = h1x(fp16) @ g2_W^T
    gemm_h8<0, false, true, false, true><<<dim3(2, 512, 1), blkG, 0, stream>>>(
        H1X, G2W, NUL, h2h, 512, 512, 256, 0);

    // 5) gat2 attention + pool + layernorm: h2h fp16 -> normed fp16
    gat2_attn_kernel<<<dim3(4096), blk, 0, stream>>>(
        h2h, miss, g2_al, g2_ar, g2_b, ln_g, ln_b, normed);

    // 6) head1: hid fp32 = relu(normed(fp16) @ h_W1^T + h_b1)
    gemm_h8<1, false, false, true, false><<<dim3(2, 128, 1), blkG, 0, stream>>>(
        N4, HW1, HB1, hid, 256, 256, 256, 0);

    // 7) head2: out[16384,8]
    head2_kernel<<<dim3(512), blk, 0, stream>>>(hid, h_W2, h_b2, out);
}